// Round 5
// baseline (2564.286 us; speedup 1.0000x reference)
//
#include <hip/hip_runtime.h>
#include <hip/hip_bf16.h>
#include <math.h>

#define NNODES 100000
#define NEDGES 1600000
#define EN     1700000      // edges + self loops
#define F_IN   256
#define F_MID  128
#define HID    128
#define NG     128
#define NOUT   64
#define SCAN_CHUNK 2048
#define NCHUNK ((NNODES + SCAN_CHUNK - 1) / SCAN_CHUNK)   // 49

typedef unsigned int  u32;
typedef unsigned short u16;

__device__ __forceinline__ float bfl(u32 u) { return __uint_as_float(u << 16); }
__device__ __forceinline__ float bfh(u32 u) { return __uint_as_float(u & 0xFFFF0000u); }
__device__ __forceinline__ u32 f2bf(float f) {           // round-to-nearest-even
    u32 x = __float_as_uint(f);
    return (x + 0x7FFFu + ((x >> 16) & 1u)) >> 16;
}

// ---------------------------------------------------------------- init
__global__ __launch_bounds__(256) void k_init(int* deg, float* gs, float* pooled) {
    int i = blockIdx.x * 256 + threadIdx.x;
    if (i < NNODES) deg[i] = 1;                 // self loop
    if (i < NG) gs[i] = 0.f;
    if (i < NG * HID) pooled[i] = 0.f;
}

// ---------------------------------------------------------------- CSR build (keyed by SRC for push-scatter)
__global__ __launch_bounds__(256) void k_count(const int* __restrict__ ei, int* deg) {
    int e = blockIdx.x * 256 + threadIdx.x;
    if (e >= NEDGES) return;
    atomicAdd(&deg[ei[e]], 1);                  // count by src
}

__global__ __launch_bounds__(256) void k_scan_chunk(const int* __restrict__ deg,
                                                    int* rowptr, int* part) {
    __shared__ int sums[256];
    int c = blockIdx.x, t = threadIdx.x;
    int base = c * SCAN_CHUNK;
    int v[8]; int s = 0;
#pragma unroll
    for (int i = 0; i < 8; i++) {
        int idx = base + t * 8 + i;
        v[i] = (idx < NNODES) ? deg[idx] : 0;
        s += v[i];
    }
    sums[t] = s;
    __syncthreads();
    for (int off = 1; off < 256; off <<= 1) {
        int x = (t >= off) ? sums[t - off] : 0;
        __syncthreads();
        sums[t] += x;
        __syncthreads();
    }
    int run = (t == 0) ? 0 : sums[t - 1];
#pragma unroll
    for (int i = 0; i < 8; i++) {
        int idx = base + t * 8 + i;
        if (idx < NNODES) rowptr[idx] = run;
        run += v[i];
    }
    if (t == 255) part[c] = sums[255];
}

__global__ void k_scan_part(int* part, int nc) {
    if (threadIdx.x == 0) {
        int run = 0;
        for (int c = 0; c < nc; c++) { int v = part[c]; part[c] = run; run += v; }
    }
}

__global__ __launch_bounds__(256) void k_scan_add(int* rowptr, int* cursor,
                                                  const int* __restrict__ part) {
    int i = blockIdx.x * 256 + threadIdx.x;
    if (i >= NNODES) return;
    int v = rowptr[i] + part[i >> 11];
    rowptr[i] = v;
    cursor[i] = v;
}

__global__ __launch_bounds__(256) void k_fill(const int* __restrict__ ei,
                                              int* cursor, int* srcs, int* dsts) {
    int e = blockIdx.x * 256 + threadIdx.x;
    if (e >= EN) return;
    int src, dst;
    if (e < NEDGES) { src = ei[e]; dst = ei[NEDGES + e]; }
    else            { src = dst = e - NEDGES; }
    int pos = atomicAdd(&cursor[src], 1);       // slot in src-CSR
    srcs[pos] = src;
    dsts[pos] = dst;
}

// ---------------------------------------------------------------- zero acc + ssum
__global__ __launch_bounds__(256) void k_zero(float4* acc4, float* ssum) {
    int i = blockIdx.x * 256 + threadIdx.x;     // 3.2M float4
    acc4[i] = make_float4(0.f, 0.f, 0.f, 0.f);
    if (i < NNODES) ssum[i] = 0.f;
}

// ---------------------------------------------------------------- per-edge coefficients (src-CSR order)
// meta[i] = (dst, ev);  ssum[dst] += ev.  Softmax without max subtraction
// (shift-invariant; logits O(1) for this input distribution).
__global__ __launch_bounds__(256) void k_coef(const int* __restrict__ srcs,
                                              const int* __restrict__ dsts,
                                              const float* __restrict__ as_,
                                              const float* __restrict__ ad_,
                                              int2* __restrict__ meta,
                                              float* __restrict__ ssum) {
    int e = blockIdx.x * 256 + threadIdx.x;
    if (e >= EN) return;
    int s = srcs[e], d = dsts[e];
    float al = as_[s] + ad_[d];
    al = (al > 0.f) ? al : 0.2f * al;
    float ev = __expf(al);
    meta[e] = make_int2(d, __float_as_int(ev));
    atomicAdd(&ssum[d], ev);
}

// ---------------------------------------------------------------- GEMM (C[M,128] = A[M,K] @ B[K,128]) -> bf16 C (paired words)
template <int K, bool ABF>
__global__ __launch_bounds__(256) void k_gemm(const void* __restrict__ Av,
                                              const float* __restrict__ B,
                                              u16* __restrict__ C, int M) {
    __shared__ float As[16][128];
    __shared__ float Bs[16][128];
    int bm = blockIdx.x * 128;
    int tid = threadIdx.x;
    int tx = tid & 15, ty = tid >> 4;
    float acc[8][8] = {};
    for (int k0 = 0; k0 < K; k0 += 16) {
#pragma unroll
        for (int q = tid; q < 512; q += 256) {       // A tile -> As[k][m] (transposed)
            int m = q >> 2, kq = (q & 3) << 2;
            int row = bm + m;
            if (ABF) {
                const u16* A = (const u16*)Av;
                uint2 v = make_uint2(0u, 0u);
                if (row < M) v = *(const uint2*)(A + (size_t)row * K + k0 + kq);
                As[kq + 0][m] = bfl(v.x); As[kq + 1][m] = bfh(v.x);
                As[kq + 2][m] = bfl(v.y); As[kq + 3][m] = bfh(v.y);
            } else {
                const float* A = (const float*)Av;
                float4 v = make_float4(0.f, 0.f, 0.f, 0.f);
                if (row < M) v = *(const float4*)(A + (size_t)row * K + k0 + kq);
                As[kq + 0][m] = v.x; As[kq + 1][m] = v.y;
                As[kq + 2][m] = v.z; As[kq + 3][m] = v.w;
            }
        }
#pragma unroll
        for (int q = tid; q < 512; q += 256) {       // B tile
            int kk = q >> 5, n4 = (q & 31) << 2;
            *(float4*)(&Bs[kk][n4]) = *(const float4*)(B + (size_t)(k0 + kk) * 128 + n4);
        }
        __syncthreads();
#pragma unroll
        for (int kk = 0; kk < 16; kk++) {
            float a[8], b[8];
            *(float4*)(a)     = *(float4*)(&As[kk][ty * 8]);
            *(float4*)(a + 4) = *(float4*)(&As[kk][ty * 8 + 4]);
            *(float4*)(b)     = *(float4*)(&Bs[kk][tx * 8]);
            *(float4*)(b + 4) = *(float4*)(&Bs[kk][tx * 8 + 4]);
#pragma unroll
            for (int i = 0; i < 8; i++)
#pragma unroll
                for (int j = 0; j < 8; j++)
                    acc[i][j] = fmaf(a[i], b[j], acc[i][j]);
        }
        __syncthreads();
    }
#pragma unroll
    for (int i = 0; i < 8; i++) {
        int row = bm + ty * 8 + i;
        if (row < M) {
            uint4 o;
            o.x = f2bf(acc[i][0]) | (f2bf(acc[i][1]) << 16);
            o.y = f2bf(acc[i][2]) | (f2bf(acc[i][3]) << 16);
            o.z = f2bf(acc[i][4]) | (f2bf(acc[i][5]) << 16);
            o.w = f2bf(acc[i][6]) | (f2bf(acc[i][7]) << 16);
            *(uint4*)(C + (size_t)row * 128 + tx * 8) = o;
        }
    }
}

// ---------------------------------------------------------------- attention dot products (wave per node, bf16 h)
__global__ __launch_bounds__(256) void k_dots(const u32* __restrict__ h,
                                              const float* __restrict__ asrc,
                                              const float* __restrict__ adst,
                                              float* as_, float* ad_) {
    int wid = (blockIdx.x * 256 + threadIdx.x) >> 6;
    int lane = threadIdx.x & 63;
    if (wid >= NNODES) return;
    u32 u = h[(size_t)wid * 64 + lane];
    float vx = bfl(u), vy = bfh(u);
    float2 as2 = ((const float2*)asrc)[lane];
    float2 ad2 = ((const float2*)adst)[lane];
    float s = vx * as2.x + vy * as2.y;
    float d = vx * ad2.x + vy * ad2.y;
#pragma unroll
    for (int off = 32; off; off >>= 1) {
        s += __shfl_xor(s, off);
        d += __shfl_xor(d, off);
    }
    if (lane == 0) { as_[wid] = s; ad_[wid] = d; }
}

// ---------------------------------------------------------------- push-scatter (wave per SRC node)
// h[src] row read ONCE (sequential); per edge: 2 fire-and-forget f32 atomics
// into acc[dst] (dense 128B lines, lane owns features {l, l+64}).
// No load latency on the per-edge critical path.
__global__ __launch_bounds__(256) void k_scatter(
    const u32* __restrict__ h, const int2* __restrict__ meta,
    const int* __restrict__ rowptr, const int* __restrict__ rowend,
    float* __restrict__ acc) {
    int wid = (blockIdx.x * 256 + threadIdx.x) >> 6;
    int lane = threadIdx.x & 63;
    if (wid >= NNODES) return;
    int row = rowptr[wid];
    int end = rowend[wid];
    // feature `lane` lives in word lane>>1 (parity lane&1); feature lane+64 in word 32+(lane>>1)
    u32 wlo = h[(size_t)wid * 64 + (lane >> 1)];
    u32 whi = h[(size_t)wid * 64 + 32 + (lane >> 1)];
    float hx = (lane & 1) ? bfh(wlo) : bfl(wlo);   // feature lane
    float hy = (lane & 1) ? bfh(whi) : bfl(whi);   // feature lane+64
    int e = row;
    for (; e + 4 <= end; e += 4) {
        int4 m01 = *(const int4*)(meta + e);
        int4 m23 = *(const int4*)(meta + e + 2);
        float e0 = __int_as_float(m01.y), e1 = __int_as_float(m01.w);
        float e2 = __int_as_float(m23.y), e3 = __int_as_float(m23.w);
        float* b0 = acc + (size_t)m01.x * 128;
        float* b1 = acc + (size_t)m01.z * 128;
        float* b2 = acc + (size_t)m23.x * 128;
        float* b3 = acc + (size_t)m23.z * 128;
        atomicAdd(b0 + lane, e0 * hx);      atomicAdd(b0 + 64 + lane, e0 * hy);
        atomicAdd(b1 + lane, e1 * hx);      atomicAdd(b1 + 64 + lane, e1 * hy);
        atomicAdd(b2 + lane, e2 * hx);      atomicAdd(b2 + 64 + lane, e2 * hy);
        atomicAdd(b3 + lane, e3 * hx);      atomicAdd(b3 + 64 + lane, e3 * hy);
    }
    for (; e < end; e++) {
        int2 m = meta[e];
        float ev = __int_as_float(m.y);
        float* b = acc + (size_t)m.x * 128;
        atomicAdd(b + lane, ev * hx);
        atomicAdd(b + 64 + lane, ev * hy);
    }
}

// ---------------------------------------------------------------- normalize + bias (+relu) (+gate) (wave per node)
template <bool RELU, bool OUTBF, bool GATE>
__global__ __launch_bounds__(256) void k_norm(
    const float* __restrict__ acc, const float* __restrict__ ssum,
    const float* __restrict__ bias, void* __restrict__ outv,
    const float* __restrict__ gateW, const float* __restrict__ gateB,
    float* __restrict__ gatev, float* __restrict__ gs,
    const int* __restrict__ batch) {
    int wid = (blockIdx.x * 256 + threadIdx.x) >> 6;
    int lane = threadIdx.x & 63;
    if (wid >= NNODES) return;
    float inv = 1.f / (ssum[wid] + 1e-16f);
    float o0 = acc[(size_t)wid * 128 + lane] * inv + bias[lane];          // feature lane
    float o1 = acc[(size_t)wid * 128 + 64 + lane] * inv + bias[lane + 64];// feature lane+64
    if (RELU) { o0 = fmaxf(o0, 0.f); o1 = fmaxf(o1, 0.f); }
    if (OUTBF) {
        // repack to paired bf16 words: word w = (feature 2w, feature 2w+1)
        int w2  = (2 * lane) & 63, w2b = (2 * lane + 1) & 63;
        float t0 = __shfl(o0, w2),  t1 = __shfl(o1, w2);
        float s0 = __shfl(o0, w2b), s1 = __shfl(o1, w2b);
        float flo = (lane < 32) ? t0 : t1;
        float fhi = (lane < 32) ? s0 : s1;
        ((u32*)outv)[(size_t)wid * 64 + lane] = f2bf(flo) | (f2bf(fhi) << 16);
    } else {
        float* o = (float*)outv;
        o[(size_t)wid * 128 + lane] = o0;
        o[(size_t)wid * 128 + 64 + lane] = o1;
    }
    if (GATE) {
        float g = o0 * gateW[lane] + o1 * gateW[lane + 64];
#pragma unroll
        for (int off = 32; off; off >>= 1) g += __shfl_xor(g, off);
        if (lane == 0) {
            float ge = __expf(g + gateB[0]);   // no max subtraction (shift-invariant)
            gatev[wid] = ge;
            atomicAdd(&gs[batch[wid]], ge);
        }
    }
}

// ---------------------------------------------------------------- attention pooling (batch is sorted)
__global__ __launch_bounds__(128) void k_pool(const float* __restrict__ h,
                                              const float* __restrict__ gatev,
                                              const float* __restrict__ gs,
                                              const int* __restrict__ batch,
                                              float* pooled) {
    int t = threadIdx.x;  // feature
    int chunk = (NNODES + gridDim.x - 1) / gridDim.x;
    int s0 = blockIdx.x * chunk;
    int s1 = s0 + chunk; if (s1 > NNODES) s1 = NNODES;
    if (s0 >= s1) return;
    int curg = batch[s0];
    float invs = 1.f / (gs[curg] + 1e-16f);
    float acc = 0.f;
    for (int i = s0; i < s1; i++) {
        int g = batch[i];
        if (g != curg) {
            atomicAdd(&pooled[curg * 128 + t], acc);
            acc = 0.f; curg = g;
            invs = 1.f / (gs[g] + 1e-16f);
        }
        acc += h[(size_t)i * 128 + t] * (gatev[i] * invs);
    }
    atomicAdd(&pooled[curg * 128 + t], acc);
}

// ---------------------------------------------------------------- final: relu(pooled) @ lin_W + lin_b
__global__ __launch_bounds__(64) void k_final(const float* __restrict__ pooled,
                                              const float* __restrict__ linW,
                                              const float* __restrict__ linb,
                                              float* __restrict__ out) {
    __shared__ float rowv[128];
    int g = blockIdx.x, t = threadIdx.x;
    rowv[t]      = fmaxf(pooled[g * 128 + t], 0.f);
    rowv[t + 64] = fmaxf(pooled[g * 128 + 64 + t], 0.f);
    __syncthreads();
    float acc = linb[t];
#pragma unroll 8
    for (int k = 0; k < 128; k++) acc = fmaf(rowv[k], linW[k * 64 + t], acc);
    out[g * 64 + t] = acc;
}

// ---------------------------------------------------------------- launch
extern "C" void kernel_launch(void* const* d_in, const int* in_sizes, int n_in,
                              void* d_out, int out_size, void* d_ws, size_t ws_size,
                              hipStream_t stream) {
    const float* x     = (const float*)d_in[0];
    const int*   ei    = (const int*)d_in[1];
    const int*   batch = (const int*)d_in[2];
    const float* W1    = (const float*)d_in[3];
    const float* a1s   = (const float*)d_in[4];
    const float* a1d   = (const float*)d_in[5];
    const float* b1    = (const float*)d_in[6];
    const float* W2    = (const float*)d_in[7];
    const float* a2s   = (const float*)d_in[8];
    const float* a2d   = (const float*)d_in[9];
    const float* b2    = (const float*)d_in[10];
    const float* gateW = (const float*)d_in[11];
    const float* gateB = (const float*)d_in[12];
    const float* linW  = (const float*)d_in[13];
    const float* linb  = (const float*)d_in[14];
    float* out = (float*)d_out;

    char* p = (char*)d_ws;
    auto alloc = [&](size_t bytes) -> void* {
        void* r = (void*)p;
        p += (bytes + 255) & ~(size_t)255;
        return r;
    };
    u16*   hb     = (u16*)alloc((size_t)NNODES * 128 * 2);   // GEMM out (bf16 paired words)
    u16*   h1a    = (u16*)alloc((size_t)NNODES * 128 * 2);   // conv1 agg out (bf16)
    // bufF (conv2 fp32 out) aliases hb+h1a (both dead by the time it's written)
    float* bufF   = (float*)hb;
    float* acc    = (float*)alloc((size_t)NNODES * 128 * 4); // scatter accumulator
    float* as_    = (float*)alloc((size_t)NNODES * 4);
    float* ad_    = (float*)alloc((size_t)NNODES * 4);
    float* gatev  = (float*)alloc((size_t)NNODES * 4);
    float* ssum   = (float*)alloc((size_t)NNODES * 4);
    int*   deg    = (int*)alloc((size_t)NNODES * 4);
    int*   rowptr = (int*)alloc((size_t)NNODES * 4);
    int*   cursor = (int*)alloc((size_t)NNODES * 4);
    int*   srcs   = (int*)alloc((size_t)EN * 4);
    int*   dsts   = (int*)alloc((size_t)EN * 4);
    int2*  meta   = (int2*)alloc((size_t)EN * 8);
    int*   part   = (int*)alloc(64 * 4);
    float* gs     = (float*)alloc(NG * 4);
    float* pooled = (float*)alloc((size_t)NG * HID * 4);

    const int gN   = (NNODES + 255) / 256;        // 391
    const int gE   = (NEDGES + 255) / 256;
    const int gEN  = (EN + 255) / 256;
    const int gW   = (NNODES + 3) / 4;            // wave-per-node, 4 waves/block
    const int gZ   = (NNODES * 32 + 255) / 256;   // float4 zero of acc

    // src-CSR build (same graph for both convs)
    k_init<<<gN, 256, 0, stream>>>(deg, gs, pooled);
    k_count<<<gE, 256, 0, stream>>>(ei, deg);
    k_scan_chunk<<<NCHUNK, 256, 0, stream>>>(deg, rowptr, part);
    k_scan_part<<<1, 64, 0, stream>>>(part, NCHUNK);
    k_scan_add<<<gN, 256, 0, stream>>>(rowptr, cursor, part);
    k_fill<<<gEN, 256, 0, stream>>>(ei, cursor, srcs, dsts);
    // after k_fill, cursor[n] == row end

    // conv1
    k_gemm<256, false><<<(NNODES + 127) / 128, 256, 0, stream>>>(x, W1, hb, NNODES);
    k_dots<<<gW, 256, 0, stream>>>((const u32*)hb, a1s, a1d, as_, ad_);
    k_zero<<<gZ, 256, 0, stream>>>((float4*)acc, ssum);
    k_coef<<<gEN, 256, 0, stream>>>(srcs, dsts, as_, ad_, meta, ssum);
    k_scatter<<<gW, 256, 0, stream>>>((const u32*)hb, meta, rowptr, cursor, acc);
    k_norm<true, true, false><<<gW, 256, 0, stream>>>(acc, ssum, b1, h1a,
                                                      nullptr, nullptr, nullptr,
                                                      nullptr, nullptr);
    // conv2
    k_gemm<128, true><<<(NNODES + 127) / 128, 256, 0, stream>>>(h1a, W2, hb, NNODES);
    k_dots<<<gW, 256, 0, stream>>>((const u32*)hb, a2s, a2d, as_, ad_);
    k_zero<<<gZ, 256, 0, stream>>>((float4*)acc, ssum);
    k_coef<<<gEN, 256, 0, stream>>>(srcs, dsts, as_, ad_, meta, ssum);
    k_scatter<<<gW, 256, 0, stream>>>((const u32*)hb, meta, rowptr, cursor, acc);
    k_norm<false, false, true><<<gW, 256, 0, stream>>>(acc, ssum, b2, bufF,
                                                       gateW, gateB, gatev, gs, batch);
    // global attention pooling + final linear
    k_pool<<<512, 128, 0, stream>>>(bufF, gatev, gs, batch, pooled);
    k_final<<<NG, 64, 0, stream>>>(pooled, linW, linb, out);
}

// Round 6
// 1216.519 us; speedup vs baseline: 2.1079x; 2.1079x over previous
//
#include <hip/hip_runtime.h>
#include <hip/hip_bf16.h>
#include <math.h>

#define NNODES 100000
#define NEDGES 1600000
#define EN     1700000      // edges + self loops
#define F_IN   256
#define F_MID  128
#define HID    128
#define NG     128
#define NOUT   64
#define SCAN_CHUNK 2048
#define NCHUNK ((NNODES + SCAN_CHUNK - 1) / SCAN_CHUNK)   // 49
#define CHUNK  8            // edges gathered per async batch

typedef unsigned int  u32;
typedef unsigned short u16;

__device__ __forceinline__ float bfl(u32 u) { return __uint_as_float(u << 16); }
__device__ __forceinline__ float bfh(u32 u) { return __uint_as_float(u & 0xFFFF0000u); }
__device__ __forceinline__ u32 f2bf(float f) {           // round-to-nearest-even
    u32 x = __float_as_uint(f);
    return (x + 0x7FFFu + ((x >> 16) & 1u)) >> 16;
}

// async gather: lane l of the wave pulls g[l] (4B) into ldsbase+4l.
// ldsbase must be wave-uniform; global address is per-lane (VGPR).
__device__ __forceinline__ void gload_lds4(const u32* g, u32* ldsbase) {
    __builtin_amdgcn_global_load_lds(
        (const __attribute__((address_space(1))) u32*)(uintptr_t)g,
        (__attribute__((address_space(3))) u32*)(u32)(uintptr_t)ldsbase,
        4, 0, 0);
}

// ---------------------------------------------------------------- init
__global__ __launch_bounds__(256) void k_init(int* deg, float* gs, float* pooled) {
    int i = blockIdx.x * 256 + threadIdx.x;
    if (i < NNODES) deg[i] = 1;                 // self loop
    if (i < NG) gs[i] = 0.f;
    if (i < NG * HID) pooled[i] = 0.f;
}

// ---------------------------------------------------------------- CSR build (keyed by dst)
__global__ __launch_bounds__(256) void k_count(const int* __restrict__ ei, int* deg) {
    int e = blockIdx.x * 256 + threadIdx.x;
    if (e >= NEDGES) return;
    atomicAdd(&deg[ei[NEDGES + e]], 1);
}

__global__ __launch_bounds__(256) void k_scan_chunk(const int* __restrict__ deg,
                                                    int* rowptr, int* part) {
    __shared__ int sums[256];
    int c = blockIdx.x, t = threadIdx.x;
    int base = c * SCAN_CHUNK;
    int v[8]; int s = 0;
#pragma unroll
    for (int i = 0; i < 8; i++) {
        int idx = base + t * 8 + i;
        v[i] = (idx < NNODES) ? deg[idx] : 0;
        s += v[i];
    }
    sums[t] = s;
    __syncthreads();
    for (int off = 1; off < 256; off <<= 1) {
        int x = (t >= off) ? sums[t - off] : 0;
        __syncthreads();
        sums[t] += x;
        __syncthreads();
    }
    int run = (t == 0) ? 0 : sums[t - 1];
#pragma unroll
    for (int i = 0; i < 8; i++) {
        int idx = base + t * 8 + i;
        if (idx < NNODES) rowptr[idx] = run;
        run += v[i];
    }
    if (t == 255) part[c] = sums[255];
}

__global__ void k_scan_part(int* part, int nc) {
    if (threadIdx.x == 0) {
        int run = 0;
        for (int c = 0; c < nc; c++) { int v = part[c]; part[c] = run; run += v; }
    }
}

__global__ __launch_bounds__(256) void k_scan_add(int* rowptr, int* cursor,
                                                  const int* __restrict__ part) {
    int i = blockIdx.x * 256 + threadIdx.x;
    if (i >= NNODES) return;
    int v = rowptr[i] + part[i >> 11];
    rowptr[i] = v;
    cursor[i] = v;
}

__global__ __launch_bounds__(256) void k_fill(const int* __restrict__ ei,
                                              int* cursor, int2* meta0) {
    int e = blockIdx.x * 256 + threadIdx.x;
    if (e >= EN) return;
    int src, dst;
    if (e < NEDGES) { src = ei[e]; dst = ei[NEDGES + e]; }
    else            { src = dst = e - NEDGES; }
    int pos = atomicAdd(&cursor[dst], 1);
    meta0[pos] = make_int2(src, dst);
}

// ---------------------------------------------------------------- per-edge coefficients (dst-CSR order)
// meta1[i] = (src, exp(leakyrelu(as_[src]+ad_[dst])))  -- softmax without max
// subtraction (shift-invariant; logits O(1) for this input distribution).
__global__ __launch_bounds__(256) void k_coef(const int2* __restrict__ meta0,
                                              const float* __restrict__ as_,
                                              const float* __restrict__ ad_,
                                              int2* __restrict__ meta1) {
    int e = blockIdx.x * 256 + threadIdx.x;
    if (e >= EN) return;
    int2 sd = meta0[e];
    float al = as_[sd.x] + ad_[sd.y];
    al = (al > 0.f) ? al : 0.2f * al;
    meta1[e] = make_int2(sd.x, __float_as_int(__expf(al)));
}

// ---------------------------------------------------------------- GEMM (C[M,128] = A[M,K] @ B[K,128]) -> bf16 C (paired words)
template <int K, bool ABF>
__global__ __launch_bounds__(256) void k_gemm(const void* __restrict__ Av,
                                              const float* __restrict__ B,
                                              u16* __restrict__ C, int M) {
    __shared__ float As[16][128];
    __shared__ float Bs[16][128];
    int bm = blockIdx.x * 128;
    int tid = threadIdx.x;
    int tx = tid & 15, ty = tid >> 4;
    float acc[8][8] = {};
    for (int k0 = 0; k0 < K; k0 += 16) {
#pragma unroll
        for (int q = tid; q < 512; q += 256) {       // A tile -> As[k][m] (transposed)
            int m = q >> 2, kq = (q & 3) << 2;
            int row = bm + m;
            if (ABF) {
                const u16* A = (const u16*)Av;
                uint2 v = make_uint2(0u, 0u);
                if (row < M) v = *(const uint2*)(A + (size_t)row * K + k0 + kq);
                As[kq + 0][m] = bfl(v.x); As[kq + 1][m] = bfh(v.x);
                As[kq + 2][m] = bfl(v.y); As[kq + 3][m] = bfh(v.y);
            } else {
                const float* A = (const float*)Av;
                float4 v = make_float4(0.f, 0.f, 0.f, 0.f);
                if (row < M) v = *(const float4*)(A + (size_t)row * K + k0 + kq);
                As[kq + 0][m] = v.x; As[kq + 1][m] = v.y;
                As[kq + 2][m] = v.z; As[kq + 3][m] = v.w;
            }
        }
#pragma unroll
        for (int q = tid; q < 512; q += 256) {       // B tile
            int kk = q >> 5, n4 = (q & 31) << 2;
            *(float4*)(&Bs[kk][n4]) = *(const float4*)(B + (size_t)(k0 + kk) * 128 + n4);
        }
        __syncthreads();
#pragma unroll
        for (int kk = 0; kk < 16; kk++) {
            float a[8], b[8];
            *(float4*)(a)     = *(float4*)(&As[kk][ty * 8]);
            *(float4*)(a + 4) = *(float4*)(&As[kk][ty * 8 + 4]);
            *(float4*)(b)     = *(float4*)(&Bs[kk][tx * 8]);
            *(float4*)(b + 4) = *(float4*)(&Bs[kk][tx * 8 + 4]);
#pragma unroll
            for (int i = 0; i < 8; i++)
#pragma unroll
                for (int j = 0; j < 8; j++)
                    acc[i][j] = fmaf(a[i], b[j], acc[i][j]);
        }
        __syncthreads();
    }
#pragma unroll
    for (int i = 0; i < 8; i++) {
        int row = bm + ty * 8 + i;
        if (row < M) {
            uint4 o;
            o.x = f2bf(acc[i][0]) | (f2bf(acc[i][1]) << 16);
            o.y = f2bf(acc[i][2]) | (f2bf(acc[i][3]) << 16);
            o.z = f2bf(acc[i][4]) | (f2bf(acc[i][5]) << 16);
            o.w = f2bf(acc[i][6]) | (f2bf(acc[i][7]) << 16);
            *(uint4*)(C + (size_t)row * 128 + tx * 8) = o;
        }
    }
}

// ---------------------------------------------------------------- attention dot products (wave per node, bf16 h)
__global__ __launch_bounds__(256) void k_dots(const u32* __restrict__ h,
                                              const float* __restrict__ asrc,
                                              const float* __restrict__ adst,
                                              float* as_, float* ad_) {
    int wid = (blockIdx.x * 256 + threadIdx.x) >> 6;
    int lane = threadIdx.x & 63;
    if (wid >= NNODES) return;
    u32 u = h[(size_t)wid * 64 + lane];
    float vx = bfl(u), vy = bfh(u);
    float2 as2 = ((const float2*)asrc)[lane];
    float2 ad2 = ((const float2*)adst)[lane];
    float s = vx * as2.x + vy * as2.y;
    float d = vx * ad2.x + vy * ad2.y;
#pragma unroll
    for (int off = 32; off; off >>= 1) {
        s += __shfl_xor(s, off);
        d += __shfl_xor(d, off);
    }
    if (lane == 0) { as_[wid] = s; ad_[wid] = d; }
}

// ---------------------------------------------------------------- GAT aggregation (wave per dst node)
// Async-gather pipeline: per 8-edge chunk, issue 8 fire-and-forget
// global_load_lds row-gathers (per-lane global addr, wave-uniform LDS dest),
// ONE vmcnt(0) wait, then LDS reads + FMA. Breaks the per-edge register
// dependency chain that capped MLP in R2-R4. Lane owns features {2l,2l+1}.
template <bool RELU, bool GATE, bool OUTBF>
__global__ __launch_bounds__(256) void k_agg(
    const u32* __restrict__ h, const int2* __restrict__ meta,
    const int* __restrict__ rowptr, const int* __restrict__ rowend,
    const float* __restrict__ bias, void* __restrict__ outv,
    const float* __restrict__ gateW, const float* __restrict__ gateB,
    float* __restrict__ gatev, float* __restrict__ gs,
    const int* __restrict__ batch) {
    __shared__ u32 lbuf[4][CHUNK * 64];          // 8 KB: wave-private row slots
    int tid = threadIdx.x;
    int w = tid >> 6, lane = tid & 63;
    int wid = blockIdx.x * 4 + w;
    if (wid >= NNODES) return;
    int row = rowptr[wid];
    int dg = rowend[wid] - row;
    const int2* mp = meta + row;
    u32* wb = &lbuf[w][0];

    float ssum = 0.f, ax = 0.f, ay = 0.f;
    for (int cb = 0; cb < dg; cb += CHUNK) {
        // fence: prior chunk's ds_reads must retire before DMA overwrites lbuf
        asm volatile("s_waitcnt lgkmcnt(0)" ::: "memory");
        int2 mm[CHUNK];
#pragma unroll
        for (int j = 0; j < CHUNK; j++) {        // uniform meta loads (clamped tail)
            int idx = cb + j;
            mm[j] = mp[(idx < dg) ? idx : dg - 1];
        }
#pragma unroll
        for (int j = 0; j < CHUNK; j++)          // 8 async row gathers, no dest regs
            gload_lds4(h + (size_t)mm[j].x * 64 + lane, wb + j * 64);
        asm volatile("s_waitcnt vmcnt(0)" ::: "memory");
#pragma unroll
        for (int j = 0; j < CHUNK; j++) {
            float ev = ((cb + j) < dg) ? __int_as_float(mm[j].y) : 0.f;
            u32 u = wb[j * 64 + lane];
            ssum += ev;                          // all lanes identical -> no reduce
            ax = fmaf(ev, bfl(u), ax);
            ay = fmaf(ev, bfh(u), ay);
        }
    }

    float inv = 1.f / (ssum + 1e-16f);
    float2 b2v = ((const float2*)bias)[lane];
    float o0 = ax * inv + b2v.x;
    float o1 = ay * inv + b2v.y;
    if (RELU) { o0 = fmaxf(o0, 0.f); o1 = fmaxf(o1, 0.f); }
    if (OUTBF) {
        ((u32*)outv)[(size_t)wid * 64 + lane] = f2bf(o0) | (f2bf(o1) << 16);
    } else {
        ((float2*)((float*)outv + (size_t)wid * 128))[lane] = make_float2(o0, o1);
    }
    if (GATE) {
        float2 gw = ((const float2*)gateW)[lane];
        float g = o0 * gw.x + o1 * gw.y;
#pragma unroll
        for (int off = 32; off; off >>= 1) g += __shfl_xor(g, off);
        if (lane == 0) {
            float ge = __expf(g + gateB[0]);   // no max subtraction (shift-invariant)
            gatev[wid] = ge;
            atomicAdd(&gs[batch[wid]], ge);
        }
    }
}

// ---------------------------------------------------------------- attention pooling (batch is sorted)
__global__ __launch_bounds__(128) void k_pool(const float* __restrict__ h,
                                              const float* __restrict__ gatev,
                                              const float* __restrict__ gs,
                                              const int* __restrict__ batch,
                                              float* pooled) {
    int t = threadIdx.x;  // feature pair index: h stored as [node][128] fp32, pairs (2l,2l+1) at [2l],[2l+1]
    int chunk = (NNODES + gridDim.x - 1) / gridDim.x;
    int s0 = blockIdx.x * chunk;
    int s1 = s0 + chunk; if (s1 > NNODES) s1 = NNODES;
    if (s0 >= s1) return;
    int curg = batch[s0];
    float invs = 1.f / (gs[curg] + 1e-16f);
    float acc = 0.f;
    for (int i = s0; i < s1; i++) {
        int g = batch[i];
        if (g != curg) {
            atomicAdd(&pooled[curg * 128 + t], acc);
            acc = 0.f; curg = g;
            invs = 1.f / (gs[g] + 1e-16f);
        }
        acc += h[(size_t)i * 128 + t] * (gatev[i] * invs);
    }
    atomicAdd(&pooled[curg * 128 + t], acc);
}

// ---------------------------------------------------------------- final: relu(pooled) @ lin_W + lin_b
// pooled layout: feature f at pooled[g*128 + perm(f)] where conv2 wrote pairs
// (2l,2l+1) to slots (l, l+64)?? -- NO: conv2 OUTBF=false writes float2 (o0,o1)
// = features (2l, 2l+1) at slots (2l, 2l+1): standard row-major. k_pool keeps it.
__global__ __launch_bounds__(64) void k_final(const float* __restrict__ pooled,
                                              const float* __restrict__ linW,
                                              const float* __restrict__ linb,
                                              float* __restrict__ out) {
    __shared__ float rowv[128];
    int g = blockIdx.x, t = threadIdx.x;
    rowv[t]      = fmaxf(pooled[g * 128 + t], 0.f);
    rowv[t + 64] = fmaxf(pooled[g * 128 + 64 + t], 0.f);
    __syncthreads();
    float acc = linb[t];
#pragma unroll 8
    for (int k = 0; k < 128; k++) acc = fmaf(rowv[k], linW[k * 64 + t], acc);
    out[g * 64 + t] = acc;
}

// ---------------------------------------------------------------- launch
extern "C" void kernel_launch(void* const* d_in, const int* in_sizes, int n_in,
                              void* d_out, int out_size, void* d_ws, size_t ws_size,
                              hipStream_t stream) {
    const float* x     = (const float*)d_in[0];
    const int*   ei    = (const int*)d_in[1];
    const int*   batch = (const int*)d_in[2];
    const float* W1    = (const float*)d_in[3];
    const float* a1s   = (const float*)d_in[4];
    const float* a1d   = (const float*)d_in[5];
    const float* b1    = (const float*)d_in[6];
    const float* W2    = (const float*)d_in[7];
    const float* a2s   = (const float*)d_in[8];
    const float* a2d   = (const float*)d_in[9];
    const float* b2    = (const float*)d_in[10];
    const float* gateW = (const float*)d_in[11];
    const float* gateB = (const float*)d_in[12];
    const float* linW  = (const float*)d_in[13];
    const float* linb  = (const float*)d_in[14];
    float* out = (float*)d_out;

    char* p = (char*)d_ws;
    auto alloc = [&](size_t bytes) -> void* {
        void* r = (void*)p;
        p += (bytes + 255) & ~(size_t)255;
        return r;
    };
    u16*   hb     = (u16*)alloc((size_t)NNODES * 128 * 2);   // GEMM out (bf16 paired words)
    // region: h1a (bf16 conv1 out) + meta0 both dead before bufF (conv2 fp32 out) is written
    char*  region = (char*)alloc((size_t)NNODES * 128 * 4);
    u16*   h1a    = (u16*)region;                            // 25.6 MB, dead after gemm2
    int2*  meta0  = (int2*)(region + (size_t)NNODES * 128 * 2); // 13.6 MB, dead after coef2
    float* bufF   = (float*)region;                          // 51.2 MB, written by agg2
    int2*  meta1  = (int2*)alloc((size_t)EN * 8);
    float* as_    = (float*)alloc((size_t)NNODES * 4);
    float* ad_    = (float*)alloc((size_t)NNODES * 4);
    float* gatev  = (float*)alloc((size_t)NNODES * 4);
    int*   deg    = (int*)alloc((size_t)NNODES * 4);
    int*   rowptr = (int*)alloc((size_t)NNODES * 4);
    int*   cursor = (int*)alloc((size_t)NNODES * 4);
    int*   part   = (int*)alloc(64 * 4);
    float* gs     = (float*)alloc(NG * 4);
    float* pooled = (float*)alloc((size_t)NG * HID * 4);

    const int gN   = (NNODES + 255) / 256;        // 391
    const int gE   = (NEDGES + 255) / 256;
    const int gEN  = (EN + 255) / 256;
    const int gW   = (NNODES + 3) / 4;            // wave-per-node, 4 waves/block

    // dst-CSR build (same graph for both convs)
    k_init<<<gN, 256, 0, stream>>>(deg, gs, pooled);
    k_count<<<gE, 256, 0, stream>>>(ei, deg);
    k_scan_chunk<<<NCHUNK, 256, 0, stream>>>(deg, rowptr, part);
    k_scan_part<<<1, 64, 0, stream>>>(part, NCHUNK);
    k_scan_add<<<gN, 256, 0, stream>>>(rowptr, cursor, part);
    k_fill<<<gEN, 256, 0, stream>>>(ei, cursor, meta0);
    // after k_fill, cursor[n] == row end

    // conv1
    k_gemm<256, false><<<(NNODES + 127) / 128, 256, 0, stream>>>(x, W1, hb, NNODES);
    k_dots<<<gW, 256, 0, stream>>>((const u32*)hb, a1s, a1d, as_, ad_);
    k_coef<<<gEN, 256, 0, stream>>>(meta0, as_, ad_, meta1);
    k_agg<true, false, true><<<gW, 256, 0, stream>>>((const u32*)hb, meta1,
                                                     rowptr, cursor, b1, h1a,
                                                     nullptr, nullptr, nullptr,
                                                     nullptr, nullptr);
    // conv2
    k_gemm<128, true><<<(NNODES + 127) / 128, 256, 0, stream>>>(h1a, W2, hb, NNODES);
    k_dots<<<gW, 256, 0, stream>>>((const u32*)hb, a2s, a2d, as_, ad_);
    k_coef<<<gEN, 256, 0, stream>>>(meta0, as_, ad_, meta1);
    k_agg<false, true, false><<<gW, 256, 0, stream>>>((const u32*)hb, meta1,
                                                      rowptr, cursor, b2, bufF,
                                                      gateW, gateB, gatev, gs, batch);
    // global attention pooling + final linear
    k_pool<<<512, 128, 0, stream>>>(bufF, gatev, gs, batch, pooled);
    k_final<<<NG, 64, 0, stream>>>(pooled, linW, linb, out);
}